// Round 1
// 851.912 us; speedup vs baseline: 1.0630x; 1.0630x over previous
//
#include <hip/hip_runtime.h>
#include <hip/hip_fp16.h>
#include <stdint.h>

typedef _Float16 half2v __attribute__((ext_vector_type(2)));
typedef _Float16 half4v __attribute__((ext_vector_type(4)));
typedef _Float16 half8v __attribute__((ext_vector_type(8)));
typedef float    float4v __attribute__((ext_vector_type(4)));

#define KDIM 2048
#define PDIM 512
#define MROWS 36864   // B*F*N = 32*32*36
#define NOBJ 36
#define NTOT 2048     // 4 * PDIM concatenated outputs
#define KT   32       // KDIM / 64

// ---------------- global -> LDS direct copy, 16B per lane ----------------
__device__ __forceinline__ void gload_lds16(const void* g, void* l) {
    using gptr_t = const __attribute__((address_space(1))) unsigned int*;
    using lptr_t = __attribute__((address_space(3))) unsigned int*;
    __builtin_amdgcn_global_load_lds((gptr_t)(uintptr_t)g,
                                     (lptr_t)(uint32_t)(uintptr_t)l,
                                     16, 0, 0);
}

// ---------------- kernel 0a: x fp32 -> fp16, 8 elems/thread ----------------
__global__ __launch_bounds__(256)
void cvt_x_kernel(const float* __restrict__ x, _Float16* __restrict__ xh) {
    const size_t i = ((size_t)blockIdx.x * 256 + threadIdx.x) * 8;
    float4v a = *(const float4v*)&x[i];
    float4v b = *(const float4v*)&x[i + 4];
    half8v h;
    h[0] = (_Float16)a[0]; h[1] = (_Float16)a[1];
    h[2] = (_Float16)a[2]; h[3] = (_Float16)a[3];
    h[4] = (_Float16)b[0]; h[5] = (_Float16)b[1];
    h[6] = (_Float16)b[2]; h[7] = (_Float16)b[3];
    *(half8v*)&xh[i] = h;
}

// ------- kernel 0b: W [K][P] fp32 -> Wt [n][k] fp16 (4 mats concat on n) -------
__global__ __launch_bounds__(256)
void cvt_w_kernel(const float* __restrict__ Wp, const float* __restrict__ Ws,
                  const float* __restrict__ Wq, const float* __restrict__ Wr,
                  _Float16* __restrict__ wt) {
    const int bid = blockIdx.x;
    const int mat = bid >> 10;           // 1024 tiles per matrix (64 k-tiles x 16 p-tiles)
    const int t   = bid & 1023;
    const int kt  = t >> 4;              // 0..63
    const int pt  = t & 15;              // 0..15
    const float* W = (mat == 0) ? Wp : (mat == 1) ? Ws : (mat == 2) ? Wq : Wr;

    __shared__ float tile[32][33];
    const int tx = threadIdx.x & 31;
    const int ty = threadIdx.x >> 5;     // 0..7
    #pragma unroll
    for (int r = 0; r < 4; ++r) {
        const int k = kt * 32 + ty + r * 8;
        tile[ty + r * 8][tx] = W[(size_t)k * PDIM + pt * 32 + tx];
    }
    __syncthreads();
    #pragma unroll
    for (int r = 0; r < 4; ++r) {
        const int p = pt * 32 + ty + r * 8;
        const int n = mat * PDIM + p;
        wt[(size_t)n * KDIM + kt * 32 + tx] = (_Float16)tile[tx][ty + r * 8];
    }
}

// ---------------- kernel 1: fused 4-way projection GEMM ----------------
// 256x256 tile, BK=64, 8-phase pipelined schedule (T1+T2+T3/T4+T5).
// LDS: [2 buf][2 half(128 rows)][128 rows x 8 chunks x 16B], linear dest for
// global_load_lds; bank-conflict-free via chunk XOR (row&7) baked into the
// per-lane GLOBAL source address (write side) and ds_read address (read side).
#define BARRIER() __builtin_amdgcn_s_barrier()

#define STAGE_AH(b_, kt_, h_) do {                                            \
    const _Float16* g_ = pA + (size_t)(kt_) * 64 + (size_t)(h_) * 262144;     \
    char* l_ = (char*)sA + (b_) * 32768 + (h_) * 16384 + tid * 16;            \
    gload_lds16(g_, l_);                                                      \
    gload_lds16(g_ + 131072, l_ + 8192);                                      \
} while (0)

#define STAGE_BH(b_, kt_, h_) do {                                            \
    const _Float16* g_ = pB + (size_t)(kt_) * 64 + (size_t)(h_) * 262144;     \
    char* l_ = (char*)sB + (b_) * 32768 + (h_) * 16384 + tid * 16;            \
    gload_lds16(g_, l_);                                                      \
    gload_lds16(g_ + 131072, l_ + 8192);                                      \
} while (0)

#define LOAD_AF(b_, qm_) do {                                                 \
    const char* ba_ = (const char*)sA + (b_) * 32768 + wrbase;                \
    _Pragma("unroll")                                                         \
    for (int mi = 0; mi < 4; ++mi) {                                          \
        const int ro_ = ((qm_) * 64 + mi * 16 + r15) * 128;                   \
        af[mi][0] = *(const half8v*)(ba_ + ro_ + ck0);                        \
        af[mi][1] = *(const half8v*)(ba_ + ro_ + ck1);                        \
    }                                                                         \
} while (0)

#define LOAD_BF(b_, qn_, dst_) do {                                           \
    const char* bb_ = (const char*)sB + (b_) * 32768 + wcbase;                \
    _Pragma("unroll")                                                         \
    for (int ni = 0; ni < 2; ++ni) {                                          \
        const int ro_ = (rB0 + (qn_) * 32 + ni * 16 + r15) * 128;             \
        dst_[ni][0] = *(const half8v*)(bb_ + ro_ + ck0);                      \
        dst_[ni][1] = *(const half8v*)(bb_ + ro_ + ck1);                      \
    }                                                                         \
} while (0)

#define MFMA16(mb_, nb_, bf_) do {                                            \
    _Pragma("unroll")                                                         \
    for (int mi = 0; mi < 4; ++mi)                                            \
        _Pragma("unroll")                                                     \
        for (int ni = 0; ni < 2; ++ni) {                                      \
            acc[(mb_) + mi][(nb_) + ni] = __builtin_amdgcn_mfma_f32_16x16x32_f16( \
                af[mi][0], bf_[ni][0], acc[(mb_) + mi][(nb_) + ni], 0, 0, 0); \
            acc[(mb_) + mi][(nb_) + ni] = __builtin_amdgcn_mfma_f32_16x16x32_f16( \
                af[mi][1], bf_[ni][1], acc[(mb_) + mi][(nb_) + ni], 0, 0, 0); \
        }                                                                     \
} while (0)

#define PHASE_SYNC() do {                                                     \
    BARRIER();                                                                \
    asm volatile("s_waitcnt lgkmcnt(0)" ::: "memory");                        \
    __builtin_amdgcn_sched_barrier(0);                                        \
} while (0)

// One K-tile = 4 phases. Stage plan (provably WAR-safe, see analysis):
//   P1: ds{A-q0 (8), B-q0 (4)} ; stage A(t+1) h0 -> buf^1 (opposite, free)
//   P2: ds{B-q1 (4)}           ; stage A(t+1) h1 -> buf^1
//   P3: ds{A-q1 (8)}           ; stage B(t+2) h0 -> buf   (B reads done at P2)
//   P4: ds{}                   ; stage B(t+2) h1 -> buf ; vmcnt(4) gate
#define ITER(t_, b_) do {                                                     \
    /* P1: quad (m0,n0) */                                                    \
    LOAD_AF(b_, 0); LOAD_BF(b_, 0, b0);                                       \
    if ((t_) + 1 < KT) STAGE_AH((b_) ^ 1, (t_) + 1, 0);                       \
    PHASE_SYNC();                                                             \
    __builtin_amdgcn_s_setprio(1); MFMA16(0, 0, b0);                          \
    __builtin_amdgcn_s_setprio(0); BARRIER();                                 \
    /* P2: quad (m0,n1) */                                                    \
    LOAD_BF(b_, 1, b1);                                                       \
    if ((t_) + 1 < KT) STAGE_AH((b_) ^ 1, (t_) + 1, 1);                       \
    PHASE_SYNC();                                                             \
    __builtin_amdgcn_s_setprio(1); MFMA16(0, 2, b1);                          \
    __builtin_amdgcn_s_setprio(0); BARRIER();                                 \
    /* P3: quad (m1,n1) */                                                    \
    LOAD_AF(b_, 1);                                                           \
    if ((t_) + 2 < KT) STAGE_BH(b_, (t_) + 2, 0);                             \
    PHASE_SYNC();                                                             \
    __builtin_amdgcn_s_setprio(1); MFMA16(4, 2, b1);                          \
    __builtin_amdgcn_s_setprio(0); BARRIER();                                 \
    /* P4: quad (m1,n0) — B-q0 still in regs, no ds reads */                  \
    if ((t_) + 2 < KT) STAGE_BH(b_, (t_) + 2, 1);                             \
    __builtin_amdgcn_s_setprio(1); MFMA16(4, 0, b0);                          \
    __builtin_amdgcn_s_setprio(0);                                            \
    if ((t_) + 2 < KT)      { asm volatile("s_waitcnt vmcnt(4)" ::: "memory"); } \
    else if ((t_) + 1 < KT) { asm volatile("s_waitcnt vmcnt(0)" ::: "memory"); } \
    BARRIER();                                                                \
} while (0)

__global__ __launch_bounds__(512, 2)
void proj_gemm(const _Float16* __restrict__ A, const _Float16* __restrict__ Bt,
               float* __restrict__ rfeat, _Float16* __restrict__ sg,
               _Float16* __restrict__ ph, _Float16* __restrict__ vh,
               const float* __restrict__ bp, const float* __restrict__ bs,
               const float* __restrict__ bq) {
    __shared__ _Float16 sA[2][2][8192];   // 64 KiB
    __shared__ _Float16 sB[2][2][8192];   // 64 KiB

    const int tid  = threadIdx.x;
    const int lane = tid & 63;
    const int wid  = tid >> 6;
    const int wr   = wid >> 2;            // 0..1  (M half owned by wave)
    const int wc   = wid & 3;             // 0..3  (N quarter owned by wave)
    const int r15  = lane & 15;
    const int k4   = lane >> 4;

    // bijective XCD swizzle (1152 % 8 == 0): each XCD gets 18 contiguous m-panels
    const int bid = blockIdx.x;
    const int swz = (bid & 7) * 144 + (bid >> 3);
    const int mt  = swz >> 3, nt = swz & 7;
    const int m0  = mt * 256, n0 = nt * 256;

    // staging source (swizzle baked into global address; LDS dest stays linear)
    const int srow = tid >> 3;                       // 0..63
    const int sk   = (tid & 7) ^ (srow & 7);
    const _Float16* pA = A  + (size_t)(m0 + srow) * KDIM + sk * 8;
    const _Float16* pB = Bt + (size_t)(n0 + srow) * KDIM + sk * 8;

    // ds_read swizzled chunk offsets: row&7 == r15&7 for every fragment row
    const int ck0 = ((k4)     ^ (r15 & 7)) * 16;     // kk = 0
    const int ck1 = ((4 + k4) ^ (r15 & 7)) * 16;     // kk = 1
    const int wrbase = wr * 16384;
    const int wcbase = (wc >> 1) * 16384;
    const int rB0    = (wc & 1) * 64;

    half8v af[4][2], b0[2][2], b1[2][2];
    float4v acc[8][4] = {};

    // prologue: A(0) h0/h1, B(0) h0/h1, B(1) h0/h1 ; gate leaves B(1) in flight
    STAGE_AH(0, 0, 0); STAGE_AH(0, 0, 1);
    STAGE_BH(0, 0, 0); STAGE_BH(0, 0, 1);
    STAGE_BH(1, 1, 0); STAGE_BH(1, 1, 1);
    asm volatile("s_waitcnt vmcnt(4)" ::: "memory");
    BARRIER();

    for (int tt = 0; tt < KT; tt += 2) {
        ITER(tt, 0);
        ITER(tt + 1, 1);
    }

    // epilogue: block-uniform output segment (n-span 256 never crosses 512)
    const int seg = n0 >> 9;                  // 0:proj 1:sigma 2:psi 3:r
    const int pn0 = (n0 & 511) + wc * 64;
    #pragma unroll
    for (int ni = 0; ni < 4; ++ni) {
        const int pcol = pn0 + ni * 16 + r15;
        float bias = 0.0f;
        if (seg == 0)      bias = bp[pcol];
        else if (seg == 1) bias = bs[pcol];
        else if (seg == 2) bias = bq[pcol];
        #pragma unroll
        for (int mi = 0; mi < 8; ++mi) {
            const int rb = m0 + wr * 128 + mi * 16 + k4 * 4;
            #pragma unroll
            for (int r = 0; r < 4; ++r) {
                const float val = acc[mi][ni][r] + bias;
                const size_t off = (size_t)(rb + r) * PDIM + pcol;
                if (seg == 0)      rfeat[off] = val;
                else if (seg == 1) sg[off] = (_Float16)val;
                else if (seg == 2) ph[off] = (_Float16)val;
                else               vh[off] = (_Float16)val;
            }
        }
    }
}

// ---------------- kernel 2: per-(b,f) attention, fp32 math ----------------
__global__ __launch_bounds__(256, 2)
void attn_kernel(const _Float16* __restrict__ sg, const _Float16* __restrict__ ph,
                 const _Float16* __restrict__ vh, float* __restrict__ rhat) {
    __shared__ _Float16 ss[NOBJ * 520];   // 512 + 8 pad halves per row
    __shared__ _Float16 ps[NOBJ * 520];
    __shared__ float    Ls[NOBJ * 37];

    const int tid = threadIdx.x;
    const size_t base = (size_t)blockIdx.x * (NOBJ * PDIM);

    for (int c = tid; c < (NOBJ * PDIM / 8); c += 256) {
        const int row = c >> 6;
        const int col = (c & 63) * 8;
        *(half8v*)&ss[row * 520 + col] = *(const half8v*)&sg[base + row * PDIM + col];
        *(half8v*)&ps[row * 520 + col] = *(const half8v*)&ph[base + row * PDIM + col];
    }
    __syncthreads();

    // logits: 12x12 grid of 3x3 register-blocked dot products (144 active threads)
    if (tid < 144) {
        const int i0 = (tid / 12) * 3;
        const int j0 = (tid % 12) * 3;
        float accv[3][3] = {};
        for (int p = 0; p < PDIM; p += 8) {
            half8v si[3], pj[3];
            #pragma unroll
            for (int ii = 0; ii < 3; ++ii) si[ii] = *(const half8v*)&ss[(i0 + ii) * 520 + p];
            #pragma unroll
            for (int jj = 0; jj < 3; ++jj) pj[jj] = *(const half8v*)&ps[(j0 + jj) * 520 + p];
            #pragma unroll
            for (int ii = 0; ii < 3; ++ii)
                #pragma unroll
                for (int jj = 0; jj < 3; ++jj) {
                    float t = accv[ii][jj];
                    #pragma unroll
                    for (int q = 0; q < 4; ++q) {
                        half2v x2; x2[0] = si[ii][2 * q]; x2[1] = si[ii][2 * q + 1];
                        half2v y2; y2[0] = pj[jj][2 * q]; y2[1] = pj[jj][2 * q + 1];
                        t = __builtin_amdgcn_fdot2(x2, y2, t, false);
                    }
                    accv[ii][jj] = t;
                }
        }
        #pragma unroll
        for (int ii = 0; ii < 3; ++ii)
            #pragma unroll
            for (int jj = 0; jj < 3; ++jj)
                Ls[(i0 + ii) * 37 + (j0 + jj)] = accv[ii][jj];
    }
    __syncthreads();

    // softmax per row (36 active threads), fp32
    if (tid < NOBJ) {
        float mx = -1e30f;
        for (int j = 0; j < NOBJ; ++j) mx = fmaxf(mx, Ls[tid * 37 + j]);
        float sum = 0.0f;
        for (int j = 0; j < NOBJ; ++j) {
            float e = __expf(Ls[tid * 37 + j] - mx);
            sum += e;
            Ls[tid * 37 + j] = e;
        }
        const float inv = 1.0f / sum;
        for (int j = 0; j < NOBJ; ++j) Ls[tid * 37 + j] *= inv;
    }
    __syncthreads();

    // AV: thread owns 4 cols (p4) x 18 rows (stride 2); v streamed from global
    const int p4 = (tid & 127) * 4;
    const int r0 = tid >> 7;
    float4v acc[18] = {};
    for (int j = 0; j < NOBJ; ++j) {
        half4v v4 = *(const half4v*)&vh[base + (size_t)j * PDIM + p4];
        float4v vf;
        vf[0] = (float)v4[0]; vf[1] = (float)v4[1];
        vf[2] = (float)v4[2]; vf[3] = (float)v4[3];
        #pragma unroll
        for (int m = 0; m < 18; ++m) {
            const float aw = Ls[(2 * m + r0) * 37 + j];
            acc[m] += aw * vf;
        }
    }
    #pragma unroll
    for (int m = 0; m < 18; ++m)
        *(float4v*)&rhat[base + (size_t)(2 * m + r0) * PDIM + p4] = acc[m];
}

extern "C" void kernel_launch(void* const* d_in, const int* in_sizes, int n_in,
                              void* d_out, int out_size, void* d_ws, size_t ws_size,
                              hipStream_t stream) {
    const float* x   = (const float*)d_in[0];
    const float* Wp  = (const float*)d_in[1];
    const float* bp  = (const float*)d_in[2];
    const float* Wsg = (const float*)d_in[3];
    const float* bsg = (const float*)d_in[4];
    const float* Wps = (const float*)d_in[5];
    const float* bps = (const float*)d_in[6];
    const float* Wr  = (const float*)d_in[7];
    float* out = (float*)d_out;

    // workspace layout (bytes): xh 150,994,944 | wt 8,388,608 | sig/psi/v 37,748,736 each
    char* ws = (char*)d_ws;
    _Float16* xh = (_Float16*)(ws);
    _Float16* wt = (_Float16*)(ws + 150994944UL);
    _Float16* sg = (_Float16*)(ws + 159383552UL);
    _Float16* ph = (_Float16*)(ws + 197132288UL);
    _Float16* vh = (_Float16*)(ws + 234881024UL);

    // M*K/8 / 256 = 36864 blocks, exact
    cvt_x_kernel<<<36864, 256, 0, stream>>>(x, xh);
    cvt_w_kernel<<<4096, 256, 0, stream>>>(Wp, Wsg, Wps, Wr, wt);
    // (M/256=144) x (NTOT/256=8) tiles, 512 threads, 128 KiB LDS (static)
    proj_gemm<<<144 * 8, 512, 0, stream>>>(xh, wt, out, sg, ph, vh, bp, bsg, bps);
    attn_kernel<<<1024, 256, 0, stream>>>(sg, ph, vh, out + 18874368);
}

// Round 2
// 847.343 us; speedup vs baseline: 1.0688x; 1.0054x over previous
//
#include <hip/hip_runtime.h>
#include <hip/hip_fp16.h>
#include <stdint.h>

typedef _Float16 half2v __attribute__((ext_vector_type(2)));
typedef _Float16 half4v __attribute__((ext_vector_type(4)));
typedef _Float16 half8v __attribute__((ext_vector_type(8)));
typedef float    float4v __attribute__((ext_vector_type(4)));

#define KDIM 2048
#define PDIM 512
#define MROWS 36864   // B*F*N = 32*32*36
#define NOBJ 36
#define NTOT 2048     // 4 * PDIM concatenated outputs
#define KT   32       // KDIM / 64

// ---------------- global -> LDS direct copy, 16B per lane ----------------
__device__ __forceinline__ void gload_lds16(const void* g, void* l) {
    using gptr_t = const __attribute__((address_space(1))) unsigned int*;
    using lptr_t = __attribute__((address_space(3))) unsigned int*;
    __builtin_amdgcn_global_load_lds((gptr_t)(uintptr_t)g,
                                     (lptr_t)(uint32_t)(uintptr_t)l,
                                     16, 0, 0);
}

// ---------------- kernel 0a: x fp32 -> fp16, 8 elems/thread ----------------
__global__ __launch_bounds__(256)
void cvt_x_kernel(const float* __restrict__ x, _Float16* __restrict__ xh) {
    const size_t i = ((size_t)blockIdx.x * 256 + threadIdx.x) * 8;
    float4v a = *(const float4v*)&x[i];
    float4v b = *(const float4v*)&x[i + 4];
    half8v h;
    h[0] = (_Float16)a[0]; h[1] = (_Float16)a[1];
    h[2] = (_Float16)a[2]; h[3] = (_Float16)a[3];
    h[4] = (_Float16)b[0]; h[5] = (_Float16)b[1];
    h[6] = (_Float16)b[2]; h[7] = (_Float16)b[3];
    *(half8v*)&xh[i] = h;
}

// ------- kernel 0b: W [K][P] fp32 -> Wt [n][k] fp16 (4 mats concat on n) -------
__global__ __launch_bounds__(256)
void cvt_w_kernel(const float* __restrict__ Wp, const float* __restrict__ Ws,
                  const float* __restrict__ Wq, const float* __restrict__ Wr,
                  _Float16* __restrict__ wt) {
    const int bid = blockIdx.x;
    const int mat = bid >> 10;           // 1024 tiles per matrix (64 k-tiles x 16 p-tiles)
    const int t   = bid & 1023;
    const int kt  = t >> 4;              // 0..63
    const int pt  = t & 15;              // 0..15
    const float* W = (mat == 0) ? Wp : (mat == 1) ? Ws : (mat == 2) ? Wq : Wr;

    __shared__ float tile[32][33];
    const int tx = threadIdx.x & 31;
    const int ty = threadIdx.x >> 5;     // 0..7
    #pragma unroll
    for (int r = 0; r < 4; ++r) {
        const int k = kt * 32 + ty + r * 8;
        tile[ty + r * 8][tx] = W[(size_t)k * PDIM + pt * 32 + tx];
    }
    __syncthreads();
    #pragma unroll
    for (int r = 0; r < 4; ++r) {
        const int p = pt * 32 + ty + r * 8;
        const int n = mat * PDIM + p;
        wt[(size_t)n * KDIM + kt * 32 + tx] = (_Float16)tile[tx][ty + r * 8];
    }
}

// ---------------- kernel 1: fused 4-way projection GEMM ----------------
// 256x256 tile, BK=64. 2 barrier-free regions per K-tile: ds_reads and MFMAs
// live in the SAME region so the compiler's fine-grained lgkmcnt(N) overlaps
// LDS drain with matrix-pipe work (no manual lgkmcnt(0) serialization).
// Counted vmcnt(4) at tile boundary only (T4); stage issued before compute (T3);
// XCD swizzle (T1); conflict-free chunk-XOR LDS swizzle (T2); setprio (T5).
#define BARRIER() __builtin_amdgcn_s_barrier()

#define STAGE_AH(b_, kt_, h_) do {                                            \
    const _Float16* g_ = pA + (size_t)(kt_) * 64 + (size_t)(h_) * 262144;     \
    char* l_ = (char*)sA + (b_) * 32768 + (h_) * 16384 + tid * 16;            \
    gload_lds16(g_, l_);                                                      \
    gload_lds16(g_ + 131072, l_ + 8192);                                      \
} while (0)

#define STAGE_BH(b_, kt_, h_) do {                                            \
    const _Float16* g_ = pB + (size_t)(kt_) * 64 + (size_t)(h_) * 262144;     \
    char* l_ = (char*)sB + (b_) * 32768 + (h_) * 16384 + tid * 16;            \
    gload_lds16(g_, l_);                                                      \
    gload_lds16(g_ + 131072, l_ + 8192);                                      \
} while (0)

#define LOAD_AF(b_, qm_) do {                                                 \
    const char* ba_ = (const char*)sA + (b_) * 32768 + wrbase;                \
    _Pragma("unroll")                                                         \
    for (int mi = 0; mi < 4; ++mi) {                                          \
        const int ro_ = ((qm_) * 64 + mi * 16 + r15) * 128;                   \
        af[mi][0] = *(const half8v*)(ba_ + ro_ + ck0);                        \
        af[mi][1] = *(const half8v*)(ba_ + ro_ + ck1);                        \
    }                                                                         \
} while (0)

#define LOAD_BF(b_, qn_, dst_) do {                                           \
    const char* bb_ = (const char*)sB + (b_) * 32768 + wcbase;                \
    _Pragma("unroll")                                                         \
    for (int ni = 0; ni < 2; ++ni) {                                          \
        const int ro_ = (rB0 + (qn_) * 32 + ni * 16 + r15) * 128;             \
        dst_[ni][0] = *(const half8v*)(bb_ + ro_ + ck0);                      \
        dst_[ni][1] = *(const half8v*)(bb_ + ro_ + ck1);                      \
    }                                                                         \
} while (0)

#define MFMA16(mb_, nb_, bf_) do {                                            \
    _Pragma("unroll")                                                         \
    for (int mi = 0; mi < 4; ++mi)                                            \
        _Pragma("unroll")                                                     \
        for (int ni = 0; ni < 2; ++ni) {                                      \
            acc[(mb_) + mi][(nb_) + ni] = __builtin_amdgcn_mfma_f32_16x16x32_f16( \
                af[mi][0], bf_[ni][0], acc[(mb_) + mi][(nb_) + ni], 0, 0, 0); \
            acc[(mb_) + mi][(nb_) + ni] = __builtin_amdgcn_mfma_f32_16x16x32_f16( \
                af[mi][1], bf_[ni][1], acc[(mb_) + mi][(nb_) + ni], 0, 0, 0); \
        }                                                                     \
} while (0)

// One K-tile = 2 regions:
//   R1: stage A(t+1)->buf^1 ; read B0,B1,A0 ; MFMA quadrants (m0,*)
//       [mid-barrier: all waves' B(t) reads consumed -> B region reusable]
//   R2: stage B(t+2)->buf   ; read A1       ; MFMA quadrants (m1,*)
//       [vmcnt(4) gate: A(t+1),B(t+1) landed; B(t+2) stays in flight]
#define ITER(t_, b_) do {                                                     \
    if ((t_) + 1 < KT) { STAGE_AH((b_) ^ 1, (t_) + 1, 0);                     \
                         STAGE_AH((b_) ^ 1, (t_) + 1, 1); }                   \
    LOAD_BF(b_, 0, b0); LOAD_BF(b_, 1, b1); LOAD_AF(b_, 0);                   \
    __builtin_amdgcn_s_setprio(1);                                            \
    MFMA16(0, 0, b0); MFMA16(0, 2, b1);                                       \
    __builtin_amdgcn_s_setprio(0);                                            \
    __builtin_amdgcn_sched_barrier(0);  /* pin MFMAs above the WAR fence */   \
    BARRIER();                                                                \
    if ((t_) + 2 < KT) { STAGE_BH(b_, (t_) + 2, 0);                           \
                         STAGE_BH(b_, (t_) + 2, 1); }                         \
    LOAD_AF(b_, 1);                                                           \
    __builtin_amdgcn_s_setprio(1);                                            \
    MFMA16(4, 0, b0); MFMA16(4, 2, b1);                                       \
    __builtin_amdgcn_s_setprio(0);                                            \
    if ((t_) + 2 < KT)      { asm volatile("s_waitcnt vmcnt(4)" ::: "memory"); } \
    else if ((t_) + 1 < KT) { asm volatile("s_waitcnt vmcnt(0)" ::: "memory"); } \
    BARRIER();                                                                \
} while (0)

__global__ __launch_bounds__(512, 2)
void proj_gemm(const _Float16* __restrict__ A, const _Float16* __restrict__ Bt,
               float* __restrict__ rfeat, _Float16* __restrict__ sg,
               _Float16* __restrict__ ph, _Float16* __restrict__ vh,
               const float* __restrict__ bp, const float* __restrict__ bs,
               const float* __restrict__ bq) {
    __shared__ _Float16 sA[2][2][8192];   // 64 KiB
    __shared__ _Float16 sB[2][2][8192];   // 64 KiB

    const int tid  = threadIdx.x;
    const int lane = tid & 63;
    const int wid  = tid >> 6;
    const int wr   = wid >> 2;            // 0..1  (M half owned by wave)
    const int wc   = wid & 3;             // 0..3  (N quarter owned by wave)
    const int r15  = lane & 15;
    const int k4   = lane >> 4;

    // bijective XCD swizzle (1152 % 8 == 0): each XCD gets 18 contiguous m-panels
    const int bid = blockIdx.x;
    const int swz = (bid & 7) * 144 + (bid >> 3);
    const int mt  = swz >> 3, nt = swz & 7;
    const int m0  = mt * 256, n0 = nt * 256;

    // staging source (swizzle baked into global address; LDS dest stays linear)
    const int srow = tid >> 3;                       // 0..63
    const int sk   = (tid & 7) ^ (srow & 7);
    const _Float16* pA = A  + (size_t)(m0 + srow) * KDIM + sk * 8;
    const _Float16* pB = Bt + (size_t)(n0 + srow) * KDIM + sk * 8;

    // ds_read swizzled chunk offsets: row&7 == r15&7 for every fragment row
    const int ck0 = ((k4)     ^ (r15 & 7)) * 16;     // kk = 0
    const int ck1 = ((4 + k4) ^ (r15 & 7)) * 16;     // kk = 1
    const int wrbase = wr * 16384;
    const int wcbase = (wc >> 1) * 16384;
    const int rB0    = (wc & 1) * 64;

    half8v af[4][2], b0[2][2], b1[2][2];
    float4v acc[8][4] = {};

    // prologue: A(0) h0/h1, B(0) h0/h1, B(1) h0/h1 ; gate leaves B(1) in flight
    STAGE_AH(0, 0, 0); STAGE_AH(0, 0, 1);
    STAGE_BH(0, 0, 0); STAGE_BH(0, 0, 1);
    STAGE_BH(1, 1, 0); STAGE_BH(1, 1, 1);
    asm volatile("s_waitcnt vmcnt(4)" ::: "memory");
    BARRIER();

    for (int tt = 0; tt < KT; tt += 2) {
        ITER(tt, 0);
        ITER(tt + 1, 1);
    }

    // epilogue: block-uniform output segment (n-span 256 never crosses 512)
    const int seg = n0 >> 9;                  // 0:proj 1:sigma 2:psi 3:r
    const int pn0 = (n0 & 511) + wc * 64;
    #pragma unroll
    for (int ni = 0; ni < 4; ++ni) {
        const int pcol = pn0 + ni * 16 + r15;
        float bias = 0.0f;
        if (seg == 0)      bias = bp[pcol];
        else if (seg == 1) bias = bs[pcol];
        else if (seg == 2) bias = bq[pcol];
        #pragma unroll
        for (int mi = 0; mi < 8; ++mi) {
            const int rb = m0 + wr * 128 + mi * 16 + k4 * 4;
            #pragma unroll
            for (int r = 0; r < 4; ++r) {
                const float val = acc[mi][ni][r] + bias;
                const size_t off = (size_t)(rb + r) * PDIM + pcol;
                if (seg == 0)      rfeat[off] = val;
                else if (seg == 1) sg[off] = (_Float16)val;
                else if (seg == 2) ph[off] = (_Float16)val;
                else               vh[off] = (_Float16)val;
            }
        }
    }
}

// ---------------- kernel 2: per-(b,f) attention, fp32 math ----------------
__global__ __launch_bounds__(256, 2)
void attn_kernel(const _Float16* __restrict__ sg, const _Float16* __restrict__ ph,
                 const _Float16* __restrict__ vh, float* __restrict__ rhat) {
    __shared__ _Float16 ss[NOBJ * 520];   // 512 + 8 pad halves per row
    __shared__ _Float16 ps[NOBJ * 520];
    __shared__ float    Ls[NOBJ * 37];

    const int tid = threadIdx.x;
    const size_t base = (size_t)blockIdx.x * (NOBJ * PDIM);

    for (int c = tid; c < (NOBJ * PDIM / 8); c += 256) {
        const int row = c >> 6;
        const int col = (c & 63) * 8;
        *(half8v*)&ss[row * 520 + col] = *(const half8v*)&sg[base + row * PDIM + col];
        *(half8v*)&ps[row * 520 + col] = *(const half8v*)&ph[base + row * PDIM + col];
    }
    __syncthreads();

    // logits: 12x12 grid of 3x3 register-blocked dot products (144 active threads)
    if (tid < 144) {
        const int i0 = (tid / 12) * 3;
        const int j0 = (tid % 12) * 3;
        float accv[3][3] = {};
        for (int p = 0; p < PDIM; p += 8) {
            half8v si[3], pj[3];
            #pragma unroll
            for (int ii = 0; ii < 3; ++ii) si[ii] = *(const half8v*)&ss[(i0 + ii) * 520 + p];
            #pragma unroll
            for (int jj = 0; jj < 3; ++jj) pj[jj] = *(const half8v*)&ps[(j0 + jj) * 520 + p];
            #pragma unroll
            for (int ii = 0; ii < 3; ++ii)
                #pragma unroll
                for (int jj = 0; jj < 3; ++jj) {
                    float t = accv[ii][jj];
                    #pragma unroll
                    for (int q = 0; q < 4; ++q) {
                        half2v x2; x2[0] = si[ii][2 * q]; x2[1] = si[ii][2 * q + 1];
                        half2v y2; y2[0] = pj[jj][2 * q]; y2[1] = pj[jj][2 * q + 1];
                        t = __builtin_amdgcn_fdot2(x2, y2, t, false);
                    }
                    accv[ii][jj] = t;
                }
        }
        #pragma unroll
        for (int ii = 0; ii < 3; ++ii)
            #pragma unroll
            for (int jj = 0; jj < 3; ++jj)
                Ls[(i0 + ii) * 37 + (j0 + jj)] = accv[ii][jj];
    }
    __syncthreads();

    // softmax per row (36 active threads), fp32
    if (tid < NOBJ) {
        float mx = -1e30f;
        for (int j = 0; j < NOBJ; ++j) mx = fmaxf(mx, Ls[tid * 37 + j]);
        float sum = 0.0f;
        for (int j = 0; j < NOBJ; ++j) {
            float e = __expf(Ls[tid * 37 + j] - mx);
            sum += e;
            Ls[tid * 37 + j] = e;
        }
        const float inv = 1.0f / sum;
        for (int j = 0; j < NOBJ; ++j) Ls[tid * 37 + j] *= inv;
    }
    __syncthreads();

    // AV: thread owns 4 cols (p4) x 18 rows (stride 2); v streamed from global
    const int p4 = (tid & 127) * 4;
    const int r0 = tid >> 7;
    float4v acc[18] = {};
    for (int j = 0; j < NOBJ; ++j) {
        half4v v4 = *(const half4v*)&vh[base + (size_t)j * PDIM + p4];
        float4v vf;
        vf[0] = (float)v4[0]; vf[1] = (float)v4[1];
        vf[2] = (float)v4[2]; vf[3] = (float)v4[3];
        #pragma unroll
        for (int m = 0; m < 18; ++m) {
            const float aw = Ls[(2 * m + r0) * 37 + j];
            acc[m] += aw * vf;
        }
    }
    #pragma unroll
    for (int m = 0; m < 18; ++m)
        *(float4v*)&rhat[base + (size_t)(2 * m + r0) * PDIM + p4] = acc[m];
}

extern "C" void kernel_launch(void* const* d_in, const int* in_sizes, int n_in,
                              void* d_out, int out_size, void* d_ws, size_t ws_size,
                              hipStream_t stream) {
    const float* x   = (const float*)d_in[0];
    const float* Wp  = (const float*)d_in[1];
    const float* bp  = (const float*)d_in[2];
    const float* Wsg = (const float*)d_in[3];
    const float* bsg = (const float*)d_in[4];
    const float* Wps = (const float*)d_in[5];
    const float* bps = (const float*)d_in[6];
    const float* Wr  = (const float*)d_in[7];
    float* out = (float*)d_out;

    // workspace layout (bytes): xh 150,994,944 | wt 8,388,608 | sig/psi/v 37,748,736 each
    char* ws = (char*)d_ws;
    _Float16* xh = (_Float16*)(ws);
    _Float16* wt = (_Float16*)(ws + 150994944UL);
    _Float16* sg = (_Float16*)(ws + 159383552UL);
    _Float16* ph = (_Float16*)(ws + 197132288UL);
    _Float16* vh = (_Float16*)(ws + 234881024UL);

    // M*K/8 / 256 = 36864 blocks, exact
    cvt_x_kernel<<<36864, 256, 0, stream>>>(x, xh);
    cvt_w_kernel<<<4096, 256, 0, stream>>>(Wp, Wsg, Wps, Wr, wt);
    // (M/256=144) x (NTOT/256=8) tiles, 512 threads, 128 KiB LDS (static)
    proj_gemm<<<144 * 8, 512, 0, stream>>>(xh, wt, out, sg, ph, vh, bp, bsg, bps);
    attn_kernel<<<1024, 256, 0, stream>>>(sg, ph, vh, out + 18874368);
}